// Round 12
// baseline (725.866 us; speedup 1.0000x reference)
//
#include <hip/hip_runtime.h>
#include <math.h>

typedef unsigned short u16;
typedef unsigned int   u32;
typedef __attribute__((ext_vector_type(8))) short short8;
typedef __attribute__((ext_vector_type(4))) float float4v;

#define DI __device__ __forceinline__

DI float b2f(u16 v){ return __uint_as_float(((u32)v) << 16); }
DI u16 f2b(float f){
  u32 u = __float_as_uint(f);
  u32 r = (u + 0x7fffu + ((u >> 16) & 1u)) >> 16;
  return (u16)r;
}
DI float gelu_exact(float x){ return x * 0.5f * (1.0f + erff(x * 0.70710678118654752f)); }

// Shapes: Bb=4, A=7, C=32, H=W=32, E=128, HEADS=4, d=32, L=N=224, K_tok=7168, HID=85
// x_lf flat: [196][32][32][32] f32, img=(b*49+u*7+v), elem = img*32768 + c*1024 + h*32 + w
// branch 0 (h): token l=(u,h), reduce k=(c, n=(v,w))
// branch 1 (v): token l=(v,w), reduce k=(c, n=(u,h))
//
// Verified MFMA recipe (k1_mfma R10, k8_mfma R11): mfma_f32_16x16x32_bf16, BOTH operands
// loaded as [row][k], row=lane&15, k=quad*8+j (one b128); D[m][n]: m=quad*4+reg, n=lane&15.
// LDS stride rule: row stride in 4B words must generate 16 distinct bank starts
// (e.g. 22 or 70 words), NOT 20/64 (8-way conflicts — R11's 5.4M SQ_LDS_BANK_CONFLICT).

// ---------------- K0: zero xq ----------------
__global__ __launch_bounds__(256) void k0_zero(float* __restrict__ xq)
{
  int idx = blockIdx.x * 256 + threadIdx.x;
  if (idx < 229376) xq[idx] = 0.f;
}

// ---------------- k_wprep: lin_w + proj_w f32 -> bf16 ----------------
__global__ __launch_bounds__(256) void k_wprep(const float* __restrict__ lw0,
    const float* __restrict__ lw1, const float* __restrict__ pw0,
    const float* __restrict__ pw1, u16* __restrict__ linwB, u16* __restrict__ projB)
{
  int base = blockIdx.x * 1024 + threadIdx.x;   // 3,670,016 total
  #pragma unroll
  for (int r = 0; r < 4; ++r) {
    int i = base + 256 * r;
    if (i < 1835008) {
      const float* src = (i < 917504) ? lw0 : lw1;
      linwB[i] = f2b(src[i % 917504]);
    } else if (i < 3670016) {
      int j = i - 1835008;
      const float* src = (j < 917504) ? pw0 : pw1;
      projB[j] = f2b(src[j % 917504]);
    }
  }
}

// ---------------- k8w_prep: pin/po/qkv weights -> bf16 ----------------
__global__ __launch_bounds__(256) void k8w_prep(const float* __restrict__ pin0,
    const float* __restrict__ pin1, const float* __restrict__ po0,
    const float* __restrict__ po1, const float* __restrict__ qw0,
    const float* __restrict__ qw1, u16* __restrict__ pinB, u16* __restrict__ poB,
    u16* __restrict__ qkvwB)
{
  int idx = blockIdx.x * 256 + threadIdx.x;   // 116736 total
  if (idx < 12288) {
    int cc = idx & 31;
    int r = (idx >> 5) % 96;
    int hb = (idx >> 5) / 96;       // br*2+half
    int br = hb >> 1, half = hb & 1;
    const float* p = br ? pin1 : pin0;
    pinB[idx] = (r < 85) ? f2b(p[(half * 85 + r) * 32 + cc]) : (u16)0;
  } else if (idx < 18432) {
    int j = idx - 12288;
    int r = j % 96;
    int t = j / 96;                 // br*32+cc
    int br = t >> 5, cc = t & 31;
    const float* p = br ? po1 : po0;
    poB[j] = (r < 85) ? f2b(p[cc * 85 + r]) : (u16)0;
  } else if (idx < 116736) {
    int j = idx - 18432;            // [br][384][128]
    int br = j / 49152, rest = j % 49152;
    qkvwB[j] = f2b((br ? qw1 : qw0)[rest]);
  }
}

// ---------------- K1 (MFMA): token GEMM, atomic accumulate into xq[bb][e][l] ----------------
__global__ __launch_bounds__(256) void k1_mfma(const float* __restrict__ xlf,
    const u16* __restrict__ linwB, float* __restrict__ xq)
{
  __shared__ u16 Asb[64][40];
  __shared__ u16 Wsb[128][40];
  const int ks   = blockIdx.x;   // 0..15
  const int mblk = blockIdx.y;   // 0..3
  const int bb   = blockIdx.z;   // br*4+b
  const int br = bb >> 2, b = bb & 3;
  const int tid = threadIdx.x;
  const int wid = tid >> 6, lane = tid & 63;
  const int quad = lane >> 4, r16 = lane & 15;
  const int m0s = mblk * 64 + wid * 16;
  const bool active = (m0s < 224);
  const u16* wsrc = linwB + br * 917504;

  float4v acc[8];
  #pragma unroll
  for (int nt = 0; nt < 8; ++nt) acc[nt] = (float4v){0.f, 0.f, 0.f, 0.f};

  #pragma unroll 1
  for (int step = 0; step < 14; ++step) {
    const int k0 = ks * 448 + step * 32;
    const int c   = k0 / 224;
    const int rem = k0 % 224;
    #pragma unroll
    for (int r = 0; r < 8; ++r) {
      int idx = tid + 256 * r;
      int ml = idx >> 5, kl = idx & 31;
      int l = mblk * 64 + ml;
      float val = 0.f;
      if (l < 224) {
        int u, h, v2, w2;
        if (br == 0) { u = l >> 5; h = l & 31; v2 = rem >> 5; w2 = kl; }
        else         { v2 = l >> 5; w2 = l & 31; u = rem >> 5; h = kl; }
        val = xlf[(b * 49 + u * 7 + v2) * 32768 + c * 1024 + h * 32 + w2];
      }
      Asb[ml][kl] = f2b(val);
    }
    #pragma unroll
    for (int r = 0; r < 16; ++r) {
      int idx = tid + 256 * r;
      int e = idx >> 5, kl = idx & 31;
      Wsb[e][kl] = wsrc[e * 7168 + k0 + kl];
    }
    __syncthreads();
    if (active) {
      short8 af = *(const short8*)&Asb[wid * 16 + r16][quad * 8];
      #pragma unroll
      for (int nt = 0; nt < 8; ++nt) {
        short8 bf = *(const short8*)&Wsb[nt * 16 + r16][quad * 8];
        acc[nt] = __builtin_amdgcn_mfma_f32_16x16x32_bf16(af, bf, acc[nt], 0, 0, 0);
      }
    }
    __syncthreads();
  }
  if (active) {
    #pragma unroll
    for (int nt = 0; nt < 8; ++nt) {
      int e = nt * 16 + r16;
      #pragma unroll
      for (int reg = 0; reg < 4; ++reg) {
        int tok = m0s + quad * 4 + reg;
        atomicAdd(&xq[(bb * 128 + e) * 224 + tok], acc[nt][reg]);
      }
    }
  }
}

// ---------------- K3 (MFMA): LN(E) + qkv 1x1 -> qkvp[bb][384][224] ----------------
// B = LN'd x [224 tok][128 e] bf16 in LDS (stride 140 u16 = 70 words: conflict-free);
// A = qkvwB [384][128] bf16 global b128 fragments. grid (mchunk=6, bb=8).
__global__ __launch_bounds__(256) void k3_mfma(const float* __restrict__ xq,
    const float* __restrict__ g0, const float* __restrict__ b0,
    const float* __restrict__ g1, const float* __restrict__ b1,
    const u16* __restrict__ qkvwB, float* __restrict__ qkvp)
{
  __shared__ u16 xnb[224][140];   // 62,720 B
  const int mchunk = blockIdx.x;  // 0..5
  const int bb = blockIdx.y;
  const int br = bb >> 2;
  const float* lg = br ? g1 : g0;
  const float* lb = br ? b1 : b0;
  const int tid = threadIdx.x;
  const int wid = tid >> 6, lane = tid & 63;
  const int quad = lane >> 4, r16 = lane & 15;

  // two-pass LN: pass1 load+stats+store raw bf16; pass2 normalize in place
  if (tid < 224) {
    float s = 0.f, s2 = 0.f;
    #pragma unroll 4
    for (int e = 0; e < 128; ++e) {
      float v = xq[(bb * 128 + e) * 224 + tid];
      s += v; s2 += v * v;
      xnb[tid][e] = f2b(v);
    }
    float mean = s * (1.f / 128.f);
    float var  = s2 * (1.f / 128.f) - mean * mean;
    float rs   = rsqrtf(fmaxf(var, 0.f) + 1e-6f);
    #pragma unroll 4
    for (int e = 0; e < 128; ++e) {
      float v = b2f(xnb[tid][e]);
      xnb[tid][e] = f2b((v - mean) * rs * lg[e] + lb[e]);
    }
  }
  __syncthreads();

  const int mtile = mchunk * 64 + wid * 16;   // < 384
  const u16* wsrc = qkvwB + br * 49152;
  float4v acc[14];
  #pragma unroll
  for (int nt = 0; nt < 14; ++nt) acc[nt] = (float4v){0.f, 0.f, 0.f, 0.f};
  #pragma unroll
  for (int k = 0; k < 4; ++k) {
    short8 af = *(const short8*)&wsrc[(mtile + r16) * 128 + k * 32 + quad * 8];
    #pragma unroll
    for (int nt = 0; nt < 14; ++nt) {
      short8 bf = *(const short8*)&xnb[nt * 16 + r16][k * 32 + quad * 8];
      acc[nt] = __builtin_amdgcn_mfma_f32_16x16x32_bf16(af, bf, acc[nt], 0, 0, 0);
    }
  }
  #pragma unroll
  for (int nt = 0; nt < 14; ++nt) {
    int tok = nt * 16 + r16;
    #pragma unroll
    for (int reg = 0; reg < 4; ++reg) {
      int o = mtile + quad * 4 + reg;
      qkvp[(bb * 384 + o) * 224 + tok] = acc[nt][reg];
    }
  }
}

// ---------------- K4: depthwise 3x3 over (7,32) ----------------
__global__ __launch_bounds__(256) void k4_dw(const float* __restrict__ qkvp,
    const float* __restrict__ dw0, const float* __restrict__ dw1, float* __restrict__ qkvd)
{
  int idx = blockIdx.x * 256 + threadIdx.x;  // 688128
  int l = idx % 224; int r0 = idx / 224;     // r0 = (br*4+b)*384 + o
  int o = r0 % 384;
  int br = (r0 / 384) >> 2;
  const float* dww = (br ? dw1 : dw0) + o * 9;
  int v = l >> 5, w = l & 31;
  const float* src = qkvp + r0 * 224;
  float acc = 0.f;
  #pragma unroll
  for (int dy = -1; dy <= 1; ++dy) {
    int vv = v + dy; if (vv < 0 || vv > 6) continue;
    #pragma unroll
    for (int dx = -1; dx <= 1; ++dx) {
      int ww = w + dx; if (ww < 0 || ww > 31) continue;
      acc += src[vv * 32 + ww] * dww[(dy + 1) * 3 + (dx + 1)];
    }
  }
  qkvd[idx] = acc;
}

// ---------------- K5: head split + l2norm(q,k) -> qkvn[bb][sel][h][l][d] ----------------
__global__ __launch_bounds__(256) void k5_heads(const float* __restrict__ qkvd, float* __restrict__ qkvn)
{
  __shared__ float ts[32][225];
  __shared__ float scs[224];
  const int bid = blockIdx.x;          // bb*12 + sel*4 + h, 96 blocks
  const int h = bid & 3;
  const int sel = (bid >> 2) % 3;
  const int bb = bid / 12;
  const int tid = threadIdx.x;
  const float* src = qkvd + (bb * 384 + sel * 128 + h * 32) * 224;
  for (int r = 0; r < 28; ++r) {
    int idx = tid + 256 * r;
    int d = idx / 224, l = idx % 224;
    ts[d][l] = src[d * 224 + l];
  }
  __syncthreads();
  if (tid < 224) {
    float ss = 0.f;
    for (int d = 0; d < 32; ++d) { float x = ts[d][tid]; ss += x * x; }
    scs[tid] = (sel < 2) ? (1.0f / fmaxf(sqrtf(ss), 1e-12f)) : 1.0f;
  }
  __syncthreads();
  float* dst = qkvn + ((bb * 3 + sel) * 4 + h) * 7168;
  for (int r = 0; r < 28; ++r) {
    int idx = tid + 256 * r;
    int d = idx & 31, l = idx >> 5;
    dst[l * 32 + d] = ts[d][l] * scs[l];
  }
}

// ---------------- K6: fused attention -> aoB[bb][tok][e] bf16 ----------------
__global__ __launch_bounds__(256) void k6_attn(const float* __restrict__ qkvn,
    const float* __restrict__ tmp0, const float* __restrict__ tmp1,
    const float* __restrict__ ca0,  const float* __restrict__ ca1,
    u16* __restrict__ aoB)
{
  __shared__ float qs[32][33];      // (h*8+i, d)
  __shared__ float ks[128][33];     // (h*32+jj, d)
  __shared__ float sS[32 * 228];    // (h*8+i)*228 + j
  __shared__ float mxs[32], rss[32];
  __shared__ float caf[32], tpf[4];
  const int it = blockIdx.x;        // 0..27 i-tile
  const int b = blockIdx.y, br = blockIdx.z;
  const int bb = br * 4 + b;
  const int tid = threadIdx.x;
  const float* tw = br ? tmp1 : tmp0;
  const float* cw = br ? ca1 : ca0;
  if (tid < 32) caf[tid] = cw[tid];
  if (tid < 4)  tpf[tid] = tw[tid];
  const int i0 = it * 8;
  const float* qb = qkvn + (bb * 3 + 0) * 4 * 7168;
  const float* kb = qkvn + (bb * 3 + 1) * 4 * 7168;
  const float* vb = qkvn + (bb * 3 + 2) * 4 * 7168;
  #pragma unroll
  for (int r = 0; r < 4; ++r) {
    int idx = tid + 256 * r;
    int d = idx & 31, i = (idx >> 5) & 7, h = idx >> 8;
    qs[h * 8 + i][d] = qb[h * 7168 + (i0 + i) * 32 + d];
  }
  const int hC = tid >> 6, iC = (tid >> 3) & 7, jq = tid & 7;
  for (int jt = 0; jt < 7; ++jt) {
    __syncthreads();
    #pragma unroll
    for (int r = 0; r < 16; ++r) {
      int idx = tid + 256 * r;
      int d = idx & 31, jj = (idx >> 5) & 31, h = idx >> 10;
      ks[h * 32 + jj][d] = kb[h * 7168 + (jt * 32 + jj) * 32 + d];
    }
    __syncthreads();
    float a4[4] = {0.f, 0.f, 0.f, 0.f};
    for (int d = 0; d < 32; ++d) {
      float qv = qs[hC * 8 + iC][d];
      #pragma unroll
      for (int r = 0; r < 4; ++r) a4[r] += qv * ks[hC * 32 + jq + 8 * r][d];
    }
    #pragma unroll
    for (int r = 0; r < 4; ++r)
      sS[(hC * 8 + iC) * 228 + jt * 32 + jq + 8 * r] = a4[r] * tpf[hC];
  }
  __syncthreads();
  { // softmax stats per row
    int p = tid & 7, row = tid >> 3;
    float mx = -1e30f;
    for (int q = 0; q < 28; ++q) mx = fmaxf(mx, sS[row * 228 + p + 8 * q]);
    #pragma unroll
    for (int m = 4; m >= 1; m >>= 1) mx = fmaxf(mx, __shfl_xor(mx, m));
    float es = 0.f;
    for (int q = 0; q < 28; ++q) es += expf(sS[row * 228 + p + 8 * q] - mx);
    #pragma unroll
    for (int m = 4; m >= 1; m >>= 1) es += __shfl_xor(es, m);
    if (p == 0) { mxs[row] = mx; rss[row] = 1.0f / es; }
  }
  __syncthreads();
  // attn = softmax*(1+scale)+shift, in place over sS
  for (int q = 0; q < 7; ++q) {
    int pr = tid + 256 * q;
    int i = pr / 224, j = pr % 224;
    float a1[4];
    #pragma unroll
    for (int hh = 0; hh < 4; ++hh) {
      float sv = sS[(hh * 8 + i) * 228 + j];
      float z = fmaxf(sv, 0.f); float z2 = z * z;
      a1[hh] = gelu_exact(z2) * z2;
    }
    #pragma unroll
    for (int hh = 0; hh < 4; ++hh) {
      float sc = 0.f, sh = 0.f;
      #pragma unroll
      for (int k2 = 0; k2 < 4; ++k2) { sc += caf[hh * 4 + k2] * a1[k2]; sh += caf[(hh + 4) * 4 + k2] * a1[k2]; }
      int row = hh * 8 + i;
      float at = expf(sS[row * 228 + j] - mxs[row]) * rss[row];
      sS[row * 228 + j] = at * (1.f + sc) + sh;
    }
  }
  __syncthreads();
  { // PV -> aoB bf16 [bb][tok][e]
    int d = tid & 31, rg = tid >> 5;
    float acc[4] = {0.f, 0.f, 0.f, 0.f};
    for (int j = 0; j < 224; ++j) {
      #pragma unroll
      for (int hh = 0; hh < 4; ++hh)
        acc[hh] += sS[(hh * 8 + rg) * 228 + j] * vb[hh * 7168 + j * 32 + d];
    }
    #pragma unroll
    for (int hh = 0; hh < 4; ++hh)
      aoB[(bb * 224 + i0 + rg) * 128 + hh * 32 + d] = f2b(acc[hh]);
  }
}

// ---------------- K7 (MFMA): proj GEMM + residual -> x2 (bf16) ----------------
// M = 7168 rows (c*224+n), N = 224 tok, K = 128. B = aoB staged once per block
// ([224][140] u16, conflict-free); A = projB global b128. grid (mchunk=28, bb=8).
__global__ __launch_bounds__(256) void k7_mfma(const u16* __restrict__ aoB,
    const u16* __restrict__ projB, const float* __restrict__ xlf, u16* __restrict__ x2)
{
  __shared__ u16 Bs[224][140];    // 62,720 B
  const int mchunk = blockIdx.x;  // 0..27
  const int bb = blockIdx.y;
  const int br = bb >> 2, b = bb & 3;
  const int tid = threadIdx.x;
  const int wid = tid >> 6, lane = tid & 63;
  const int quad = lane >> 4, r16 = lane & 15;
  const u16* asrc = projB + br * 917504;
  // stage B: 224 rows x 16 short8
  #pragma unroll
  for (int i = 0; i < 14; ++i) {
    int idx = tid + 256 * i;      // 3584
    int row = idx >> 4, c8 = idx & 15;
    *(short8*)&Bs[row][c8 * 8] = *(const short8*)&aoB[(bb * 224 + row) * 128 + c8 * 8];
  }
  __syncthreads();
  #pragma unroll 1
  for (int mi = 0; mi < 4; ++mi) {
    const int mbase = mchunk * 256 + (wid * 4 + mi) * 16;
    float4v acc[14];
    #pragma unroll
    for (int nt = 0; nt < 14; ++nt) acc[nt] = (float4v){0.f, 0.f, 0.f, 0.f};
    #pragma unroll
    for (int k = 0; k < 4; ++k) {
      short8 af = *(const short8*)&asrc[(mbase + r16) * 128 + k * 32 + quad * 8];
      #pragma unroll
      for (int nt = 0; nt < 14; ++nt) {
        short8 bf = *(const short8*)&Bs[nt * 16 + r16][k * 32 + quad * 8];
        acc[nt] = __builtin_amdgcn_mfma_f32_16x16x32_bf16(af, bf, acc[nt], 0, 0, 0);
      }
    }
    #pragma unroll 1
    for (int nt = 0; nt < 14; ++nt) {
      int l = nt * 16 + r16;
      #pragma unroll
      for (int reg = 0; reg < 4; ++reg) {
        int row = mbase + quad * 4 + reg;
        int c = row / 224, n = row - c * 224;
        int img, off;
        if (br == 0) { img = b * 49 + (l >> 5) * 7 + (n >> 5); off = c * 1024 + (l & 31) * 32 + (n & 31); }
        else         { img = b * 49 + (n >> 5) * 7 + (l >> 5); off = c * 1024 + (n & 31) * 32 + (l & 31); }
        float res = xlf[img * 32768 + off];
        x2[((br * 896 + b * 224 + n) * 32 + c) * 224 + l] = f2b(acc[nt][reg] + res);
      }
    }
  }
}

// ---------------- K8 (MFMA): LN(C)+pin+dw3x3+gelu gate+pout+residual ----------------
// R12: pad xnb/gsb 40 -> 44 u16 (22-word stride: 16 distinct bank starts vs 20-word's 8)
__global__ __launch_bounds__(256) void k8_mfma(u16* x2,
    const float* __restrict__ lg0, const float* __restrict__ lb0,
    const float* __restrict__ lg1, const float* __restrict__ lb1,
    const float* __restrict__ dwa0, const float* __restrict__ dwa1,
    const u16* __restrict__ pinB, const u16* __restrict__ poB)
{
  __shared__ u16 xnb[224][44];   // 19,712 B
  __shared__ u16 t1s[16][232];   //  7,424 B
  __shared__ u16 tgs[16][232];   //  7,424 B
  __shared__ u16 gsb[224][44];   // 19,712 B
  const int img = blockIdx.x;    // 0..895
  const int br  = blockIdx.y;
  const float* lg  = br ? lg1 : lg0;
  const float* lb  = br ? lb1 : lb0;
  const float* dww = br ? dwa1 : dwa0;
  const u16* pinBr = pinB + br * 2 * 96 * 32;
  const u16* poBr  = poB + br * 32 * 96;
  const int tid = threadIdx.x;
  const int wid = tid >> 6, lane = tid & 63;
  const int quad = lane >> 4, r16 = lane & 15;
  u16* src = x2 + (br * 896 + img) * 7168;

  if (tid < 224) {
    float xr[32];
    #pragma unroll
    for (int cc = 0; cc < 32; ++cc) xr[cc] = b2f(src[cc * 224 + tid]);
    float s = 0.f, s2 = 0.f;
    #pragma unroll
    for (int cc = 0; cc < 32; ++cc) { s += xr[cc]; s2 += xr[cc] * xr[cc]; }
    float mean = s * (1.f / 32.f);
    float var  = s2 * (1.f / 32.f) - mean * mean;
    float rs   = rsqrtf(fmaxf(var, 0.f) + 1e-6f);
    #pragma unroll
    for (int cc = 0; cc < 32; ++cc)
      xnb[tid][cc] = f2b((xr[cc] - mean) * rs * lg[cc] + lb[cc]);
  }
  __syncthreads();

  float4v acc[7];
  #pragma unroll
  for (int i = 0; i < 7; ++i) acc[i] = (float4v){0.f, 0.f, 0.f, 0.f};

  #pragma unroll 1
  for (int s = 0; s < 3; ++s) {
    #pragma unroll 1
    for (int hh = 0; hh < 2; ++hh) {
      const int r0 = s * 32 + hh * 16;
      #pragma unroll
      for (int i = 0; i < 7; ++i) {
        int t = wid + 4 * i;
        int m = t / 14, n = t - m * 14;
        short8 af = *(const short8*)&pinBr[((m * 96 + r0 + r16) << 5) + quad * 8];
        short8 bf = *(const short8*)&xnb[n * 16 + r16][quad * 8];
        float4v d = __builtin_amdgcn_mfma_f32_16x16x32_bf16(af, bf,
                     (float4v){0.f, 0.f, 0.f, 0.f}, 0, 0, 0);
        u16* dst = m ? &tgs[0][0] : &t1s[0][0];
        #pragma unroll
        for (int reg = 0; reg < 4; ++reg)
          dst[(quad * 4 + reg) * 232 + n * 16 + r16] = f2b(d[reg]);
      }
      __syncthreads();
      #pragma unroll 1
      for (int i = 0; i < 14; ++i) {
        int item = tid + 256 * i;          // 16*224
        int rl = item / 224, l = item - rl * 224;
        int r = r0 + rl;
        float g = 0.f;
        if (r < 85) {
          const float* w1 = dww + r * 9;
          const float* w2 = dww + (85 + r) * 9;
          int v = l >> 5, wq = l & 31;
          float d1 = 0.f, d2 = 0.f;
          #pragma unroll
          for (int dy = -1; dy <= 1; ++dy) {
            int vv = v + dy; if (vv < 0 || vv > 6) continue;
            #pragma unroll
            for (int dx = -1; dx <= 1; ++dx) {
              int ww = wq + dx; if (ww < 0 || ww > 31) continue;
              int li = vv * 32 + ww; int wi = (dy + 1) * 3 + dx + 1;
              d1 += b2f(t1s[rl][li]) * w1[wi];
              d2 += b2f(tgs[rl][li]) * w2[wi];
            }
          }
          g = gelu_exact(d1) * d2;
        }
        gsb[l][hh * 16 + rl] = f2b(g);
      }
      __syncthreads();
    }
    #pragma unroll
    for (int i = 0; i < 7; ++i) {
      int u = wid + 4 * i;
      int mt = u / 14, n = u - mt * 14;
      short8 af = *(const short8*)&poBr[(mt * 16 + r16) * 96 + s * 32 + quad * 8];
      short8 bf = *(const short8*)&gsb[n * 16 + r16][quad * 8];
      acc[i] = __builtin_amdgcn_mfma_f32_16x16x32_bf16(af, bf, acc[i], 0, 0, 0);
    }
  }
  #pragma unroll
  for (int i = 0; i < 7; ++i) {
    int u = wid + 4 * i;
    int mt = u / 14, n = u - mt * 14;
    #pragma unroll
    for (int reg = 0; reg < 4; ++reg) {
      int cc = mt * 16 + quad * 4 + reg;
      int tok = n * 16 + r16;
      int o = cc * 224 + tok;
      src[o] = f2b(b2f(src[o]) + acc[i][reg]);
    }
  }
}

// ---------------- K9a: adaptive max pool per (t, c64) ----------------
__global__ __launch_bounds__(256) void k9_pool(const u16* __restrict__ x3, float* __restrict__ gmax)
{
  __shared__ float red[4];
  const int bid = blockIdx.x;      // t*64 + c64
  const int c64 = bid & 63;
  const int t = bid >> 6;
  const int c = c64 & 31, which = c64 >> 5;
  const int b = t / 49; const int uv = t % 49; const int u = uv / 7; const int vq = uv % 7;
  const int tid = threadIdx.x;
  float mx = -1e30f;
  if (which == 0) {
    int h = tid & 31, w0 = tid >> 5;
    #pragma unroll
    for (int r = 0; r < 4; ++r) {
      int w = w0 + 8 * r;
      mx = fmaxf(mx, b2f(x3[((b * 224 + vq * 32 + w) * 32 + c) * 224 + u * 32 + h]));
    }
  } else {
    int w = tid & 31, h0 = tid >> 5;
    #pragma unroll
    for (int r = 0; r < 4; ++r) {
      int h = h0 + 8 * r;
      mx = fmaxf(mx, b2f(x3[((896 + b * 224 + u * 32 + h) * 32 + c) * 224 + vq * 32 + w]));
    }
  }
  #pragma unroll
  for (int m = 32; m >= 1; m >>= 1) mx = fmaxf(mx, __shfl_xor(mx, m));
  if ((tid & 63) == 0) red[tid >> 6] = mx;
  __syncthreads();
  if (tid == 0)
    gmax[t * 64 + c64] = fmaxf(fmaxf(red[0], red[1]), fmaxf(red[2], red[3]));
}

// ---------------- K9b: FC gate ----------------
__global__ __launch_bounds__(256) void k9_fc(const float* __restrict__ gmax,
    const float* __restrict__ f1, const float* __restrict__ f2, float* __restrict__ gate)
{
  int t = blockIdx.x * 256 + threadIdx.x;
  if (t >= 196) return;
  float g1[8];
  #pragma unroll
  for (int o = 0; o < 8; ++o) {
    float a = 0.f;
    #pragma unroll
    for (int c2 = 0; c2 < 64; ++c2) a += f1[o * 64 + c2] * gmax[t * 64 + c2];
    g1[o] = (a >= 0.f) ? a : 0.1f * a;
  }
  #pragma unroll
  for (int c2 = 0; c2 < 32; ++c2) {
    float a = 0.f;
    #pragma unroll
    for (int o = 0; o < 8; ++o) a += f2[c2 * 8 + o] * g1[o];
    gate[t * 32 + c2] = 1.f / (1.f + expf(-a));
  }
}

// ---------------- K9c: gated combine -> out[t][c][h][w] f32 ----------------
__global__ __launch_bounds__(256) void k9_final(const u16* __restrict__ x3,
    const float* __restrict__ gate, float* __restrict__ out)
{
  __shared__ float o1s[32][33];
  const int bid = blockIdx.x;   // t*32 + c
  const int c = bid & 31;
  const int t = bid >> 5;
  const int b = t / 49; const int uv = t % 49; const int u = uv / 7; const int vq = uv % 7;
  const int tid = threadIdx.x;
  const float g = gate[t * 32 + c];
  #pragma unroll
  for (int r = 0; r < 4; ++r) {
    int h = tid & 31; int w = (tid >> 5) + 8 * r;
    o1s[w][h] = b2f(x3[((b * 224 + vq * 32 + w) * 32 + c) * 224 + u * 32 + h]);
  }
  __syncthreads();
  #pragma unroll
  for (int r = 0; r < 4; ++r) {
    int w = tid & 31; int h = (tid >> 5) + 8 * r;
    float o2 = b2f(x3[((896 + b * 224 + u * 32 + h) * 32 + c) * 224 + vq * 32 + w]);
    float o1 = o1s[w][h];
    out[(t * 32 + c) * 1024 + h * 32 + w] = o1 * g + o2 * (1.f - g);
  }
}

extern "C" void kernel_launch(void* const* d_in, const int* in_sizes, int n_in,
                              void* d_out, int out_size, void* d_ws, size_t ws_size,
                              hipStream_t stream)
{
  const float* xlf    = (const float*)d_in[0];
  const float* h_lin  = (const float*)d_in[1];
  const float* h_temp = (const float*)d_in[2];
  const float* h_g1   = (const float*)d_in[3];
  const float* h_b1   = (const float*)d_in[4];
  const float* h_qkv  = (const float*)d_in[5];
  const float* h_qdw  = (const float*)d_in[6];
  const float* h_proj = (const float*)d_in[7];
  const float* h_ca   = (const float*)d_in[8];
  const float* h_ge   = (const float*)d_in[9];
  const float* h_be   = (const float*)d_in[10];
  const float* h_pin  = (const float*)d_in[11];
  const float* h_dw   = (const float*)d_in[12];
  const float* h_po   = (const float*)d_in[13];
  const float* v_lin  = (const float*)d_in[14];
  const float* v_temp = (const float*)d_in[15];
  const float* v_g1   = (const float*)d_in[16];
  const float* v_b1   = (const float*)d_in[17];
  const float* v_qkv  = (const float*)d_in[18];
  const float* v_qdw  = (const float*)d_in[19];
  const float* v_proj = (const float*)d_in[20];
  const float* v_ca   = (const float*)d_in[21];
  const float* v_ge   = (const float*)d_in[22];
  const float* v_be   = (const float*)d_in[23];
  const float* v_pin  = (const float*)d_in[24];
  const float* v_dw   = (const float*)d_in[25];
  const float* v_po   = (const float*)d_in[26];
  const float* f1     = (const float*)d_in[27];
  const float* f2     = (const float*)d_in[28];

  char* w = (char*)d_ws;
  u16*   x2    = (u16*)  (w + 0);          // 25,690,112 B
  float* xq    = (float*)(w + 25690112);   //    917,504 B
  float* qkvp  = (float*)(w + 26607616);   //  2,752,512 B (aliased by qkvn after K4)
  float* qkvd  = (float*)(w + 29360128);   //  2,752,512 B
  float* gmax  = (float*)(w + 32112640);   //     50,176 B
  float* gate  = (float*)(w + 32162816);   //     25,088 B
  u16*   pinB  = (u16*)  (w + 32187904);   //     24,576 B
  u16*   poB   = (u16*)  (w + 32212480);   //     12,288 B
  u16*   qkvwB = (u16*)  (w + 32224768);   //    196,608 B
  u16*   aoB   = (u16*)  (w + 32421376);   //    458,752 B (k6 -> k7)
  u16*   linwB = (u16*)  (w + 32880128);   //  3,670,016 B
  u16*   projB = (u16*)  (w + 36550144);   //  3,670,016 B
  float* qkvn = qkvp;                      // K5 writes (qkvp dead)
  // total ws used: 40,220,160 B (~38.4 MB; ws >= 52.6 MB proven R3)

  k0_zero  <<<896, 256, 0, stream>>>(xq);
  k_wprep  <<<3584, 256, 0, stream>>>(h_lin, v_lin, h_proj, v_proj, linwB, projB);
  k8w_prep <<<456, 256, 0, stream>>>(h_pin, v_pin, h_po, v_po, h_qkv, v_qkv, pinB, poB, qkvwB);
  k1_mfma  <<<dim3(16, 4, 8), 256, 0, stream>>>(xlf, linwB, xq);
  k3_mfma  <<<dim3(6, 8), 256, 0, stream>>>(xq, h_g1, h_b1, v_g1, v_b1, qkvwB, qkvp);
  k4_dw    <<<2688, 256, 0, stream>>>(qkvp, h_qdw, v_qdw, qkvd);
  k5_heads <<<96, 256, 0, stream>>>(qkvd, qkvn);
  k6_attn  <<<dim3(28, 4, 2), 256, 0, stream>>>(qkvn, h_temp, v_temp, h_ca, v_ca, aoB);
  k7_mfma  <<<dim3(28, 8), 256, 0, stream>>>(aoB, projB, xlf, x2);
  k8_mfma  <<<dim3(896, 2), 256, 0, stream>>>(x2, h_ge, h_be, v_ge, v_be,
                                              h_dw, v_dw, pinB, poB);
  k9_pool  <<<12544, 256, 0, stream>>>(x2, gmax);
  k9_fc    <<<1, 256, 0, stream>>>(gmax, f1, f2, gate);
  k9_final <<<6272, 256, 0, stream>>>(x2, gate, (float*)d_out);
}

// Round 13
// 663.435 us; speedup vs baseline: 1.0941x; 1.0941x over previous
//
#include <hip/hip_runtime.h>
#include <math.h>

typedef unsigned short u16;
typedef unsigned int   u32;
typedef __attribute__((ext_vector_type(8))) short short8;
typedef __attribute__((ext_vector_type(4))) short short4v;
typedef __attribute__((ext_vector_type(4))) float float4v;

#define DI __device__ __forceinline__

DI float b2f(u16 v){ return __uint_as_float(((u32)v) << 16); }
DI u16 f2b(float f){
  u32 u = __float_as_uint(f);
  u32 r = (u + 0x7fffu + ((u >> 16) & 1u)) >> 16;
  return (u16)r;
}
DI float gelu_exact(float x){ return x * 0.5f * (1.0f + erff(x * 0.70710678118654752f)); }

// Shapes: Bb=4, A=7, C=32, H=W=32, E=128, HEADS=4, d=32, L=N=224, K_tok=7168, HID=85
// x_lf flat: [196][32][32][32] f32, img=(b*49+u*7+v), elem = img*32768 + c*1024 + h*32 + w
// branch 0 (h): token l=(u,h), reduce k=(c, n=(v,w))
// branch 1 (v): token l=(v,w), reduce k=(c, n=(u,h))
//
// Verified MFMA recipe (k1 R10, k8 R11, k3/k7 R12): mfma_f32_16x16x32_bf16, operands
// loaded as [row][k], row=lane&15, k=quad*8+j (one b128); D[m][n]: m=quad*4+reg, n=lane&15.
// LDS lessons: (R11) stride-20-word rows -> 2-way b128 reads, tolerable;
// (R12) padding to 22 words kills conflicts but LDS 54272 B rounds past the ~2KiB
// granularity 3-block boundary (163840/3) -> 2 blocks/CU -> occupancy loss dominates.
// k8 budget target: total LDS <= 53248 B for 3 blocks/CU.

// ---------------- K0: zero xq ----------------
__global__ __launch_bounds__(256) void k0_zero(float* __restrict__ xq)
{
  int idx = blockIdx.x * 256 + threadIdx.x;
  if (idx < 229376) xq[idx] = 0.f;
}

// ---------------- k_wprep: lin_w + proj_w f32 -> bf16 ----------------
__global__ __launch_bounds__(256) void k_wprep(const float* __restrict__ lw0,
    const float* __restrict__ lw1, const float* __restrict__ pw0,
    const float* __restrict__ pw1, u16* __restrict__ linwB, u16* __restrict__ projB)
{
  int base = blockIdx.x * 1024 + threadIdx.x;   // 3,670,016 total
  #pragma unroll
  for (int r = 0; r < 4; ++r) {
    int i = base + 256 * r;
    if (i < 1835008) {
      const float* src = (i < 917504) ? lw0 : lw1;
      linwB[i] = f2b(src[i % 917504]);
    } else if (i < 3670016) {
      int j = i - 1835008;
      const float* src = (j < 917504) ? pw0 : pw1;
      projB[j] = f2b(src[j % 917504]);
    }
  }
}

// ---------------- k8w_prep: pin/po/qkv weights -> bf16 ----------------
__global__ __launch_bounds__(256) void k8w_prep(const float* __restrict__ pin0,
    const float* __restrict__ pin1, const float* __restrict__ po0,
    const float* __restrict__ po1, const float* __restrict__ qw0,
    const float* __restrict__ qw1, u16* __restrict__ pinB, u16* __restrict__ poB,
    u16* __restrict__ qkvwB)
{
  int idx = blockIdx.x * 256 + threadIdx.x;   // 116736 total
  if (idx < 12288) {
    int cc = idx & 31;
    int r = (idx >> 5) % 96;
    int hb = (idx >> 5) / 96;       // br*2+half
    int br = hb >> 1, half = hb & 1;
    const float* p = br ? pin1 : pin0;
    pinB[idx] = (r < 85) ? f2b(p[(half * 85 + r) * 32 + cc]) : (u16)0;
  } else if (idx < 18432) {
    int j = idx - 12288;
    int r = j % 96;
    int t = j / 96;                 // br*32+cc
    int br = t >> 5, cc = t & 31;
    const float* p = br ? po1 : po0;
    poB[j] = (r < 85) ? f2b(p[cc * 85 + r]) : (u16)0;
  } else if (idx < 116736) {
    int j = idx - 18432;            // [br][384][128]
    int br = j / 49152, rest = j % 49152;
    qkvwB[j] = f2b((br ? qw1 : qw0)[rest]);
  }
}

// ---------------- K1 (MFMA): token GEMM, atomic accumulate into xq[bb][e][l] ----------------
__global__ __launch_bounds__(256) void k1_mfma(const float* __restrict__ xlf,
    const u16* __restrict__ linwB, float* __restrict__ xq)
{
  __shared__ u16 Asb[64][40];
  __shared__ u16 Wsb[128][40];
  const int ks   = blockIdx.x;   // 0..15
  const int mblk = blockIdx.y;   // 0..3
  const int bb   = blockIdx.z;   // br*4+b
  const int br = bb >> 2, b = bb & 3;
  const int tid = threadIdx.x;
  const int wid = tid >> 6, lane = tid & 63;
  const int quad = lane >> 4, r16 = lane & 15;
  const int m0s = mblk * 64 + wid * 16;
  const bool active = (m0s < 224);
  const u16* wsrc = linwB + br * 917504;

  float4v acc[8];
  #pragma unroll
  for (int nt = 0; nt < 8; ++nt) acc[nt] = (float4v){0.f, 0.f, 0.f, 0.f};

  #pragma unroll 1
  for (int step = 0; step < 14; ++step) {
    const int k0 = ks * 448 + step * 32;
    const int c   = k0 / 224;
    const int rem = k0 % 224;
    #pragma unroll
    for (int r = 0; r < 8; ++r) {
      int idx = tid + 256 * r;
      int ml = idx >> 5, kl = idx & 31;
      int l = mblk * 64 + ml;
      float val = 0.f;
      if (l < 224) {
        int u, h, v2, w2;
        if (br == 0) { u = l >> 5; h = l & 31; v2 = rem >> 5; w2 = kl; }
        else         { v2 = l >> 5; w2 = l & 31; u = rem >> 5; h = kl; }
        val = xlf[(b * 49 + u * 7 + v2) * 32768 + c * 1024 + h * 32 + w2];
      }
      Asb[ml][kl] = f2b(val);
    }
    #pragma unroll
    for (int r = 0; r < 16; ++r) {
      int idx = tid + 256 * r;
      int e = idx >> 5, kl = idx & 31;
      Wsb[e][kl] = wsrc[e * 7168 + k0 + kl];
    }
    __syncthreads();
    if (active) {
      short8 af = *(const short8*)&Asb[wid * 16 + r16][quad * 8];
      #pragma unroll
      for (int nt = 0; nt < 8; ++nt) {
        short8 bf = *(const short8*)&Wsb[nt * 16 + r16][quad * 8];
        acc[nt] = __builtin_amdgcn_mfma_f32_16x16x32_bf16(af, bf, acc[nt], 0, 0, 0);
      }
    }
    __syncthreads();
  }
  if (active) {
    #pragma unroll
    for (int nt = 0; nt < 8; ++nt) {
      int e = nt * 16 + r16;
      #pragma unroll
      for (int reg = 0; reg < 4; ++reg) {
        int tok = m0s + quad * 4 + reg;
        atomicAdd(&xq[(bb * 128 + e) * 224 + tok], acc[nt][reg]);
      }
    }
  }
}

// ---------------- K3 (MFMA): LN(E) + qkv 1x1 -> qkvp[bb][384][224] ----------------
__global__ __launch_bounds__(256) void k3_mfma(const float* __restrict__ xq,
    const float* __restrict__ g0, const float* __restrict__ b0,
    const float* __restrict__ g1, const float* __restrict__ b1,
    const u16* __restrict__ qkvwB, float* __restrict__ qkvp)
{
  __shared__ u16 xnb[224][140];   // 62,720 B
  const int mchunk = blockIdx.x;  // 0..5
  const int bb = blockIdx.y;
  const int br = bb >> 2;
  const float* lg = br ? g1 : g0;
  const float* lb = br ? b1 : b0;
  const int tid = threadIdx.x;
  const int wid = tid >> 6, lane = tid & 63;
  const int quad = lane >> 4, r16 = lane & 15;

  if (tid < 224) {
    float s = 0.f, s2 = 0.f;
    #pragma unroll 4
    for (int e = 0; e < 128; ++e) {
      float v = xq[(bb * 128 + e) * 224 + tid];
      s += v; s2 += v * v;
      xnb[tid][e] = f2b(v);
    }
    float mean = s * (1.f / 128.f);
    float var  = s2 * (1.f / 128.f) - mean * mean;
    float rs   = rsqrtf(fmaxf(var, 0.f) + 1e-6f);
    #pragma unroll 4
    for (int e = 0; e < 128; ++e) {
      float v = b2f(xnb[tid][e]);
      xnb[tid][e] = f2b((v - mean) * rs * lg[e] + lb[e]);
    }
  }
  __syncthreads();

  const int mtile = mchunk * 64 + wid * 16;   // < 384
  const u16* wsrc = qkvwB + br * 49152;
  float4v acc[14];
  #pragma unroll
  for (int nt = 0; nt < 14; ++nt) acc[nt] = (float4v){0.f, 0.f, 0.f, 0.f};
  #pragma unroll
  for (int k = 0; k < 4; ++k) {
    short8 af = *(const short8*)&wsrc[(mtile + r16) * 128 + k * 32 + quad * 8];
    #pragma unroll
    for (int nt = 0; nt < 14; ++nt) {
      short8 bf = *(const short8*)&xnb[nt * 16 + r16][k * 32 + quad * 8];
      acc[nt] = __builtin_amdgcn_mfma_f32_16x16x32_bf16(af, bf, acc[nt], 0, 0, 0);
    }
  }
  #pragma unroll
  for (int nt = 0; nt < 14; ++nt) {
    int tok = nt * 16 + r16;
    #pragma unroll
    for (int reg = 0; reg < 4; ++reg) {
      int o = mtile + quad * 4 + reg;
      qkvp[(bb * 384 + o) * 224 + tok] = acc[nt][reg];
    }
  }
}

// ---------------- K4: depthwise 3x3 over (7,32) ----------------
__global__ __launch_bounds__(256) void k4_dw(const float* __restrict__ qkvp,
    const float* __restrict__ dw0, const float* __restrict__ dw1, float* __restrict__ qkvd)
{
  int idx = blockIdx.x * 256 + threadIdx.x;  // 688128
  int l = idx % 224; int r0 = idx / 224;     // r0 = (br*4+b)*384 + o
  int o = r0 % 384;
  int br = (r0 / 384) >> 2;
  const float* dww = (br ? dw1 : dw0) + o * 9;
  int v = l >> 5, w = l & 31;
  const float* src = qkvp + r0 * 224;
  float acc = 0.f;
  #pragma unroll
  for (int dy = -1; dy <= 1; ++dy) {
    int vv = v + dy; if (vv < 0 || vv > 6) continue;
    #pragma unroll
    for (int dx = -1; dx <= 1; ++dx) {
      int ww = w + dx; if (ww < 0 || ww > 31) continue;
      acc += src[vv * 32 + ww] * dww[(dy + 1) * 3 + (dx + 1)];
    }
  }
  qkvd[idx] = acc;
}

// ---------------- K5: head split + l2norm(q,k) -> qkvn[bb][sel][h][l][d] ----------------
__global__ __launch_bounds__(256) void k5_heads(const float* __restrict__ qkvd, float* __restrict__ qkvn)
{
  __shared__ float ts[32][225];
  __shared__ float scs[224];
  const int bid = blockIdx.x;          // bb*12 + sel*4 + h, 96 blocks
  const int h = bid & 3;
  const int sel = (bid >> 2) % 3;
  const int bb = bid / 12;
  const int tid = threadIdx.x;
  const float* src = qkvd + (bb * 384 + sel * 128 + h * 32) * 224;
  for (int r = 0; r < 28; ++r) {
    int idx = tid + 256 * r;
    int d = idx / 224, l = idx % 224;
    ts[d][l] = src[d * 224 + l];
  }
  __syncthreads();
  if (tid < 224) {
    float ss = 0.f;
    for (int d = 0; d < 32; ++d) { float x = ts[d][tid]; ss += x * x; }
    scs[tid] = (sel < 2) ? (1.0f / fmaxf(sqrtf(ss), 1e-12f)) : 1.0f;
  }
  __syncthreads();
  float* dst = qkvn + ((bb * 3 + sel) * 4 + h) * 7168;
  for (int r = 0; r < 28; ++r) {
    int idx = tid + 256 * r;
    int d = idx & 31, l = idx >> 5;
    dst[l * 32 + d] = ts[d][l] * scs[l];
  }
}

// ---------------- K6: fused attention -> aoB[bb][tok][e] bf16 ----------------
__global__ __launch_bounds__(256) void k6_attn(const float* __restrict__ qkvn,
    const float* __restrict__ tmp0, const float* __restrict__ tmp1,
    const float* __restrict__ ca0,  const float* __restrict__ ca1,
    u16* __restrict__ aoB)
{
  __shared__ float qs[32][33];      // (h*8+i, d)
  __shared__ float ks[128][33];     // (h*32+jj, d)
  __shared__ float sS[32 * 228];    // (h*8+i)*228 + j
  __shared__ float mxs[32], rss[32];
  __shared__ float caf[32], tpf[4];
  const int it = blockIdx.x;        // 0..27 i-tile
  const int b = blockIdx.y, br = blockIdx.z;
  const int bb = br * 4 + b;
  const int tid = threadIdx.x;
  const float* tw = br ? tmp1 : tmp0;
  const float* cw = br ? ca1 : ca0;
  if (tid < 32) caf[tid] = cw[tid];
  if (tid < 4)  tpf[tid] = tw[tid];
  const int i0 = it * 8;
  const float* qb = qkvn + (bb * 3 + 0) * 4 * 7168;
  const float* kb = qkvn + (bb * 3 + 1) * 4 * 7168;
  const float* vb = qkvn + (bb * 3 + 2) * 4 * 7168;
  #pragma unroll
  for (int r = 0; r < 4; ++r) {
    int idx = tid + 256 * r;
    int d = idx & 31, i = (idx >> 5) & 7, h = idx >> 8;
    qs[h * 8 + i][d] = qb[h * 7168 + (i0 + i) * 32 + d];
  }
  const int hC = tid >> 6, iC = (tid >> 3) & 7, jq = tid & 7;
  for (int jt = 0; jt < 7; ++jt) {
    __syncthreads();
    #pragma unroll
    for (int r = 0; r < 16; ++r) {
      int idx = tid + 256 * r;
      int d = idx & 31, jj = (idx >> 5) & 31, h = idx >> 10;
      ks[h * 32 + jj][d] = kb[h * 7168 + (jt * 32 + jj) * 32 + d];
    }
    __syncthreads();
    float a4[4] = {0.f, 0.f, 0.f, 0.f};
    for (int d = 0; d < 32; ++d) {
      float qv = qs[hC * 8 + iC][d];
      #pragma unroll
      for (int r = 0; r < 4; ++r) a4[r] += qv * ks[hC * 32 + jq + 8 * r][d];
    }
    #pragma unroll
    for (int r = 0; r < 4; ++r)
      sS[(hC * 8 + iC) * 228 + jt * 32 + jq + 8 * r] = a4[r] * tpf[hC];
  }
  __syncthreads();
  { // softmax stats per row
    int p = tid & 7, row = tid >> 3;
    float mx = -1e30f;
    for (int q = 0; q < 28; ++q) mx = fmaxf(mx, sS[row * 228 + p + 8 * q]);
    #pragma unroll
    for (int m = 4; m >= 1; m >>= 1) mx = fmaxf(mx, __shfl_xor(mx, m));
    float es = 0.f;
    for (int q = 0; q < 28; ++q) es += expf(sS[row * 228 + p + 8 * q] - mx);
    #pragma unroll
    for (int m = 4; m >= 1; m >>= 1) es += __shfl_xor(es, m);
    if (p == 0) { mxs[row] = mx; rss[row] = 1.0f / es; }
  }
  __syncthreads();
  // attn = softmax*(1+scale)+shift, in place over sS
  for (int q = 0; q < 7; ++q) {
    int pr = tid + 256 * q;
    int i = pr / 224, j = pr % 224;
    float a1[4];
    #pragma unroll
    for (int hh = 0; hh < 4; ++hh) {
      float sv = sS[(hh * 8 + i) * 228 + j];
      float z = fmaxf(sv, 0.f); float z2 = z * z;
      a1[hh] = gelu_exact(z2) * z2;
    }
    #pragma unroll
    for (int hh = 0; hh < 4; ++hh) {
      float sc = 0.f, sh = 0.f;
      #pragma unroll
      for (int k2 = 0; k2 < 4; ++k2) { sc += caf[hh * 4 + k2] * a1[k2]; sh += caf[(hh + 4) * 4 + k2] * a1[k2]; }
      int row = hh * 8 + i;
      float at = expf(sS[row * 228 + j] - mxs[row]) * rss[row];
      sS[row * 228 + j] = at * (1.f + sc) + sh;
    }
  }
  __syncthreads();
  { // PV -> aoB bf16 [bb][tok][e]
    int d = tid & 31, rg = tid >> 5;
    float acc[4] = {0.f, 0.f, 0.f, 0.f};
    for (int j = 0; j < 224; ++j) {
      #pragma unroll
      for (int hh = 0; hh < 4; ++hh)
        acc[hh] += sS[(hh * 8 + rg) * 228 + j] * vb[hh * 7168 + j * 32 + d];
    }
    #pragma unroll
    for (int hh = 0; hh < 4; ++hh)
      aoB[(bb * 224 + i0 + rg) * 128 + hh * 32 + d] = f2b(acc[hh]);
  }
}

// ---------------- K7 (MFMA): proj GEMM + residual -> x2 (bf16) ----------------
__global__ __launch_bounds__(256) void k7_mfma(const u16* __restrict__ aoB,
    const u16* __restrict__ projB, const float* __restrict__ xlf, u16* __restrict__ x2)
{
  __shared__ u16 Bs[224][140];    // 62,720 B
  const int mchunk = blockIdx.x;  // 0..27
  const int bb = blockIdx.y;
  const int br = bb >> 2, b = bb & 3;
  const int tid = threadIdx.x;
  const int wid = tid >> 6, lane = tid & 63;
  const int quad = lane >> 4, r16 = lane & 15;
  const u16* asrc = projB + br * 917504;
  #pragma unroll
  for (int i = 0; i < 14; ++i) {
    int idx = tid + 256 * i;      // 3584
    int row = idx >> 4, c8 = idx & 15;
    *(short8*)&Bs[row][c8 * 8] = *(const short8*)&aoB[(bb * 224 + row) * 128 + c8 * 8];
  }
  __syncthreads();
  #pragma unroll 1
  for (int mi = 0; mi < 4; ++mi) {
    const int mbase = mchunk * 256 + (wid * 4 + mi) * 16;
    float4v acc[14];
    #pragma unroll
    for (int nt = 0; nt < 14; ++nt) acc[nt] = (float4v){0.f, 0.f, 0.f, 0.f};
    #pragma unroll
    for (int k = 0; k < 4; ++k) {
      short8 af = *(const short8*)&asrc[(mbase + r16) * 128 + k * 32 + quad * 8];
      #pragma unroll
      for (int nt = 0; nt < 14; ++nt) {
        short8 bf = *(const short8*)&Bs[nt * 16 + r16][k * 32 + quad * 8];
        acc[nt] = __builtin_amdgcn_mfma_f32_16x16x32_bf16(af, bf, acc[nt], 0, 0, 0);
      }
    }
    #pragma unroll 1
    for (int nt = 0; nt < 14; ++nt) {
      int l = nt * 16 + r16;
      #pragma unroll
      for (int reg = 0; reg < 4; ++reg) {
        int row = mbase + quad * 4 + reg;
        int c = row / 224, n = row - c * 224;
        int img, off;
        if (br == 0) { img = b * 49 + (l >> 5) * 7 + (n >> 5); off = c * 1024 + (l & 31) * 32 + (n & 31); }
        else         { img = b * 49 + (n >> 5) * 7 + (l >> 5); off = c * 1024 + (n & 31) * 32 + (l & 31); }
        float res = xlf[img * 32768 + off];
        x2[((br * 896 + b * 224 + n) * 32 + c) * 224 + l] = f2b(acc[nt][reg] + res);
      }
    }
  }
}

// ---------------- K8 (MFMA): LN(C)+pin+dw3x3+gelu gate+pout+residual ----------------
// R13: xnb back to 40 (R11 occupancy profile); t1s/tgs merged into interleaved
// t12[16][233] u32 (odd stride -> no quad write conflicts; dw loop 9 u32 reads
// instead of 18 u16); gsb 44 with explicit b64-pair fragment loads (8B-aligned).
// LDS 17920+14912+19712 = 52544 -> rounds 53248, x3 = 159744 <= 163840 -> 3 blocks/CU.
__global__ __launch_bounds__(256) void k8_mfma(u16* x2,
    const float* __restrict__ lg0, const float* __restrict__ lb0,
    const float* __restrict__ lg1, const float* __restrict__ lb1,
    const float* __restrict__ dwa0, const float* __restrict__ dwa1,
    const u16* __restrict__ pinB, const u16* __restrict__ poB)
{
  __shared__ u16 xnb[224][40];   // 17,920 B
  __shared__ u32 t12[16][233];   // 14,912 B  (t1 lo | tg hi)
  __shared__ u16 gsb[224][44];   // 19,712 B
  const int img = blockIdx.x;    // 0..895
  const int br  = blockIdx.y;
  const float* lg  = br ? lg1 : lg0;
  const float* lb  = br ? lb1 : lb0;
  const float* dww = br ? dwa1 : dwa0;
  const u16* pinBr = pinB + br * 2 * 96 * 32;
  const u16* poBr  = poB + br * 32 * 96;
  const int tid = threadIdx.x;
  const int wid = tid >> 6, lane = tid & 63;
  const int quad = lane >> 4, r16 = lane & 15;
  u16* src = x2 + (br * 896 + img) * 7168;

  if (tid < 224) {
    float xr[32];
    #pragma unroll
    for (int cc = 0; cc < 32; ++cc) xr[cc] = b2f(src[cc * 224 + tid]);
    float s = 0.f, s2 = 0.f;
    #pragma unroll
    for (int cc = 0; cc < 32; ++cc) { s += xr[cc]; s2 += xr[cc] * xr[cc]; }
    float mean = s * (1.f / 32.f);
    float var  = s2 * (1.f / 32.f) - mean * mean;
    float rs   = rsqrtf(fmaxf(var, 0.f) + 1e-6f);
    #pragma unroll
    for (int cc = 0; cc < 32; ++cc)
      xnb[tid][cc] = f2b((xr[cc] - mean) * rs * lg[cc] + lb[cc]);
  }
  __syncthreads();

  float4v acc[7];
  #pragma unroll
  for (int i = 0; i < 7; ++i) acc[i] = (float4v){0.f, 0.f, 0.f, 0.f};

  #pragma unroll 1
  for (int s = 0; s < 3; ++s) {
    #pragma unroll 1
    for (int hh = 0; hh < 2; ++hh) {
      const int r0 = s * 32 + hh * 16;
      // pin MFMA: 28 tiles (m=0 -> t1, m=1 -> tg), 7 per wave; D -> t12 u16 halves
      #pragma unroll
      for (int i = 0; i < 7; ++i) {
        int t = wid + 4 * i;
        int m = t / 14, n = t - m * 14;
        short8 af = *(const short8*)&pinBr[((m * 96 + r0 + r16) << 5) + quad * 8];
        short8 bf = *(const short8*)&xnb[n * 16 + r16][quad * 8];
        float4v d = __builtin_amdgcn_mfma_f32_16x16x32_bf16(af, bf,
                     (float4v){0.f, 0.f, 0.f, 0.f}, 0, 0, 0);
        #pragma unroll
        for (int reg = 0; reg < 4; ++reg)
          ((u16*)&t12[quad * 4 + reg][n * 16 + r16])[m] = f2b(d[reg]);
      }
      __syncthreads();
      // dw 3x3 + gelu gate -> gsb[:, hh*16 + r_loc]  (9 u32 reads per point)
      #pragma unroll 1
      for (int i = 0; i < 14; ++i) {
        int item = tid + 256 * i;          // 16*224
        int rl = item / 224, l = item - rl * 224;
        int r = r0 + rl;
        float g = 0.f;
        if (r < 85) {
          const float* w1 = dww + r * 9;
          const float* w2 = dww + (85 + r) * 9;
          int v = l >> 5, wq = l & 31;
          float d1 = 0.f, d2 = 0.f;
          #pragma unroll
          for (int dy = -1; dy <= 1; ++dy) {
            int vv = v + dy; if (vv < 0 || vv > 6) continue;
            #pragma unroll
            for (int dx = -1; dx <= 1; ++dx) {
              int ww = wq + dx; if (ww < 0 || ww > 31) continue;
              u32 p = t12[rl][vv * 32 + ww];
              int wi = (dy + 1) * 3 + dx + 1;
              d1 += b2f((u16)(p & 0xffffu)) * w1[wi];
              d2 += b2f((u16)(p >> 16)) * w2[wi];
            }
          }
          g = gelu_exact(d1) * d2;
        }
        gsb[l][hh * 16 + rl] = f2b(g);
      }
      __syncthreads();
    }
    // pout MFMA: accumulate over this 32-k super-chunk
    #pragma unroll
    for (int i = 0; i < 7; ++i) {
      int u = wid + 4 * i;
      int mt = u / 14, n = u - mt * 14;
      short8 af = *(const short8*)&poBr[(mt * 16 + r16) * 96 + s * 32 + quad * 8];
      const u16* gp = &gsb[n * 16 + r16][quad * 8];
      short8 bf;
      ((short4v*)&bf)[0] = *(const short4v*)gp;
      ((short4v*)&bf)[1] = *(const short4v*)(gp + 4);
      acc[i] = __builtin_amdgcn_mfma_f32_16x16x32_bf16(af, bf, acc[i], 0, 0, 0);
    }
  }
  #pragma unroll
  for (int i = 0; i < 7; ++i) {
    int u = wid + 4 * i;
    int mt = u / 14, n = u - mt * 14;
    #pragma unroll
    for (int reg = 0; reg < 4; ++reg) {
      int cc = mt * 16 + quad * 4 + reg;
      int tok = n * 16 + r16;
      int o = cc * 224 + tok;
      src[o] = f2b(b2f(src[o]) + acc[i][reg]);
    }
  }
}

// ---------------- K9a: adaptive max pool per (t, c64) ----------------
__global__ __launch_bounds__(256) void k9_pool(const u16* __restrict__ x3, float* __restrict__ gmax)
{
  __shared__ float red[4];
  const int bid = blockIdx.x;      // t*64 + c64
  const int c64 = bid & 63;
  const int t = bid >> 6;
  const int c = c64 & 31, which = c64 >> 5;
  const int b = t / 49; const int uv = t % 49; const int u = uv / 7; const int vq = uv % 7;
  const int tid = threadIdx.x;
  float mx = -1e30f;
  if (which == 0) {
    int h = tid & 31, w0 = tid >> 5;
    #pragma unroll
    for (int r = 0; r < 4; ++r) {
      int w = w0 + 8 * r;
      mx = fmaxf(mx, b2f(x3[((b * 224 + vq * 32 + w) * 32 + c) * 224 + u * 32 + h]));
    }
  } else {
    int w = tid & 31, h0 = tid >> 5;
    #pragma unroll
    for (int r = 0; r < 4; ++r) {
      int h = h0 + 8 * r;
      mx = fmaxf(mx, b2f(x3[((896 + b * 224 + u * 32 + h) * 32 + c) * 224 + vq * 32 + w]));
    }
  }
  #pragma unroll
  for (int m = 32; m >= 1; m >>= 1) mx = fmaxf(mx, __shfl_xor(mx, m));
  if ((tid & 63) == 0) red[tid >> 6] = mx;
  __syncthreads();
  if (tid == 0)
    gmax[t * 64 + c64] = fmaxf(fmaxf(red[0], red[1]), fmaxf(red[2], red[3]));
}

// ---------------- K9b: FC gate ----------------
__global__ __launch_bounds__(256) void k9_fc(const float* __restrict__ gmax,
    const float* __restrict__ f1, const float* __restrict__ f2, float* __restrict__ gate)
{
  int t = blockIdx.x * 256 + threadIdx.x;
  if (t >= 196) return;
  float g1[8];
  #pragma unroll
  for (int o = 0; o < 8; ++o) {
    float a = 0.f;
    #pragma unroll
    for (int c2 = 0; c2 < 64; ++c2) a += f1[o * 64 + c2] * gmax[t * 64 + c2];
    g1[o] = (a >= 0.f) ? a : 0.1f * a;
  }
  #pragma unroll
  for (int c2 = 0; c2 < 32; ++c2) {
    float a = 0.f;
    #pragma unroll
    for (int o = 0; o < 8; ++o) a += f2[c2 * 8 + o] * g1[o];
    gate[t * 32 + c2] = 1.f / (1.f + expf(-a));
  }
}

// ---------------- K9c: gated combine -> out[t][c][h][w] f32 ----------------
__global__ __launch_bounds__(256) void k9_final(const u16* __restrict__ x3,
    const float* __restrict__ gate, float* __restrict__ out)
{
  __shared__ float o1s[32][33];
  const int bid = blockIdx.x;   // t*32 + c
  const int c = bid & 31;
  const int t = bid >> 5;
  const int b = t / 49; const int uv = t % 49; const int u = uv / 7; const int vq = uv % 7;
  const int tid = threadIdx.x;
  const float g = gate[t * 32 + c];
  #pragma unroll
  for (int r = 0; r < 4; ++r) {
    int h = tid & 31; int w = (tid >> 5) + 8 * r;
    o1s[w][h] = b2f(x3[((b * 224 + vq * 32 + w) * 32 + c) * 224 + u * 32 + h]);
  }
  __syncthreads();
  #pragma unroll
  for (int r = 0; r < 4; ++r) {
    int w = tid & 31; int h = (tid >> 5) + 8 * r;
    float o2 = b2f(x3[((896 + b * 224 + u * 32 + h) * 32 + c) * 224 + vq * 32 + w]);
    float o1 = o1s[w][h];
    out[(t * 32 + c) * 1024 + h * 32 + w] = o1 * g + o2 * (1.f - g);
  }
}

extern "C" void kernel_launch(void* const* d_in, const int* in_sizes, int n_in,
                              void* d_out, int out_size, void* d_ws, size_t ws_size,
                              hipStream_t stream)
{
  const float* xlf    = (const float*)d_in[0];
  const float* h_lin  = (const float*)d_in[1];
  const float* h_temp = (const float*)d_in[2];
  const float* h_g1   = (const float*)d_in[3];
  const float* h_b1   = (const float*)d_in[4];
  const float* h_qkv  = (const float*)d_in[5];
  const float* h_qdw  = (const float*)d_in[6];
  const float* h_proj = (const float*)d_in[7];
  const float* h_ca   = (const float*)d_in[8];
  const float* h_ge   = (const float*)d_in[9];
  const float* h_be   = (const float*)d_in[10];
  const float* h_pin  = (const float*)d_in[11];
  const float* h_dw   = (const float*)d_in[12];
  const float* h_po   = (const float*)d_in[13];
  const float* v_lin  = (const float*)d_in[14];
  const float* v_temp = (const float*)d_in[15];
  const float* v_g1   = (const float*)d_in[16];
  const float* v_b1   = (const float*)d_in[17];
  const float* v_qkv  = (const float*)d_in[18];
  const float* v_qdw  = (const float*)d_in[19];
  const float* v_proj = (const float*)d_in[20];
  const float* v_ca   = (const float*)d_in[21];
  const float* v_ge   = (const float*)d_in[22];
  const float* v_be   = (const float*)d_in[23];
  const float* v_pin  = (const float*)d_in[24];
  const float* v_dw   = (const float*)d_in[25];
  const float* v_po   = (const float*)d_in[26];
  const float* f1     = (const float*)d_in[27];
  const float* f2     = (const float*)d_in[28];

  char* w = (char*)d_ws;
  u16*   x2    = (u16*)  (w + 0);          // 25,690,112 B
  float* xq    = (float*)(w + 25690112);   //    917,504 B
  float* qkvp  = (float*)(w + 26607616);   //  2,752,512 B (aliased by qkvn after K4)
  float* qkvd  = (float*)(w + 29360128);   //  2,752,512 B
  float* gmax  = (float*)(w + 32112640);   //     50,176 B
  float* gate  = (float*)(w + 32162816);   //     25,088 B
  u16*   pinB  = (u16*)  (w + 32187904);   //     24,576 B
  u16*   poB   = (u16*)  (w + 32212480);   //     12,288 B
  u16*   qkvwB = (u16*)  (w + 32224768);   //    196,608 B
  u16*   aoB   = (u16*)  (w + 32421376);   //    458,752 B (k6 -> k7)
  u16*   linwB = (u16*)  (w + 32880128);   //  3,670,016 B
  u16*   projB = (u16*)  (w + 36550144);   //  3,670,016 B
  float* qkvn = qkvp;                      // K5 writes (qkvp dead)
  // total ws used: 40,220,160 B (~38.4 MB; ws >= 52.6 MB proven R3)

  k0_zero  <<<896, 256, 0, stream>>>(xq);
  k_wprep  <<<3584, 256, 0, stream>>>(h_lin, v_lin, h_proj, v_proj, linwB, projB);
  k8w_prep <<<456, 256, 0, stream>>>(h_pin, v_pin, h_po, v_po, h_qkv, v_qkv, pinB, poB, qkvwB);
  k1_mfma  <<<dim3(16, 4, 8), 256, 0, stream>>>(xlf, linwB, xq);
  k3_mfma  <<<dim3(6, 8), 256, 0, stream>>>(xq, h_g1, h_b1, v_g1, v_b1, qkvwB, qkvp);
  k4_dw    <<<2688, 256, 0, stream>>>(qkvp, h_qdw, v_qdw, qkvd);
  k5_heads <<<96, 256, 0, stream>>>(qkvd, qkvn);
  k6_attn  <<<dim3(28, 4, 2), 256, 0, stream>>>(qkvn, h_temp, v_temp, h_ca, v_ca, aoB);
  k7_mfma  <<<dim3(28, 8), 256, 0, stream>>>(aoB, projB, xlf, x2);
  k8_mfma  <<<dim3(896, 2), 256, 0, stream>>>(x2, h_ge, h_be, v_ge, v_be,
                                              h_dw, v_dw, pinB, poB);
  k9_pool  <<<12544, 256, 0, stream>>>(x2, gmax);
  k9_fc    <<<1, 256, 0, stream>>>(gmax, f1, f2, gate);
  k9_final <<<6272, 256, 0, stream>>>(x2, gate, (float*)d_out);
}